// Round 1
// baseline (1246.956 us; speedup 1.0000x reference)
//
#include <hip/hip_runtime.h>

#define B_ 128
#define T_ 31
#define E_ 512
#define H_ 512
#define V_ 10000
#define A_ 2048
#define TP1 32      // T+1
#define G4 2048     // 4*H
#define NHC 4096    // rows of [W_attn_H ; W_hh]
#define MPRE 3968   // B*T

typedef unsigned short u16;
typedef __attribute__((ext_vector_type(8))) short bf16x8;
typedef __attribute__((ext_vector_type(4))) float f32x4;

__device__ __forceinline__ u16 f2b(float f) {
  union { float f; unsigned u; } x; x.f = f;
  unsigned r = x.u + 0x7fffu + ((x.u >> 16) & 1u);
  return (u16)(r >> 16);
}
__device__ __forceinline__ float sigmoidf_(float x) { return 1.f / (1.f + __expf(-x)); }

// ---------------- prep kernels ----------------

// xs_tb[t][b][e] bf16 : t=0 -> features, t>=1 -> embed[captions[b][t-1]]
__global__ __launch_bounds__(256) void prep_xs(
    u16* __restrict__ xs, const float* __restrict__ features,
    const int* __restrict__ captions, const float* __restrict__ embed) {
  int idx = blockIdx.x * 256 + threadIdx.x;       // < 32*128*512
  int e = idx & 511;
  int b = (idx >> 9) & 127;
  int t = idx >> 16;
  float v;
  if (t == 0) v = features[b * 512 + e];
  else        v = embed[(size_t)captions[b * 31 + (t - 1)] * 512 + e];
  xs[idx] = f2b(v);
}

__global__ __launch_bounds__(256) void cast_k(
    u16* __restrict__ dst, const float* __restrict__ src, int n) {
  int i = blockIdx.x * 256 + threadIdx.x;
  if (i < n) dst[i] = f2b(src[i]);
}

// W_attnE[n][k] = W_attn[n][k]  (k<512) ; Wh_comb[n][k] = W_attn[n][512+k]
__global__ __launch_bounds__(256) void prep_attn_w(
    u16* __restrict__ WattnE, u16* __restrict__ WhComb, const float* __restrict__ W_attn) {
  int i = blockIdx.x * 256 + threadIdx.x;         // < 2048*512
  int r = i >> 9, k = i & 511;
  WattnE[i] = f2b(W_attn[r * 1024 + k]);
  WhComb[i] = f2b(W_attn[r * 1024 + 512 + k]);
}

// W_attdE[e][k] = W_attd[e][k] (k<512)
__global__ __launch_bounds__(256) void prep_attdE(
    u16* __restrict__ dst, const float* __restrict__ W_attd) {
  int i = blockIdx.x * 256 + threadIdx.x;         // < 512*512
  int r = i >> 9, k = i & 511;
  dst[i] = f2b(W_attd[r * 2560 + k]);
}

// W_attdAT[a][e] = W_attd[e][512+a]   (transposed copy of attended-part)
__global__ __launch_bounds__(256) void prep_attdAT(
    u16* __restrict__ dst, const float* __restrict__ W_attd) {
  int i = blockIdx.x * 256 + threadIdx.x;         // < 2048*512
  int a = i >> 9, e = i & 511;
  dst[i] = f2b(W_attd[(size_t)e * 2560 + 512 + a]);
}

__global__ __launch_bounds__(256) void add_bias2(
    float* __restrict__ dst, const float* __restrict__ a, const float* __restrict__ b) {
  int i = blockIdx.x * 256 + threadIdx.x;
  if (i < G4) dst[i] = a[i] + b[i];
}

// ---------------- generic NT GEMM:  C[M,N] = A[M,K] * B[N,K]^T (+bias[n]) ----------------
// A, B bf16 K-contiguous. Block = 256 thr = 4 waves; tile 64x64, BK=32.
// grid: (ceil(N/64), M/64, splitk). Caller guarantees M%64==0, K%32==0, lda/ldb %8==0.
template<bool OUT_BF16, bool ATOMIC, bool NGUARD>
__global__ __launch_bounds__(256) void gemm_nt(
    const u16* __restrict__ Ag, const u16* __restrict__ Bg,
    void* __restrict__ Cout, const float* __restrict__ bias,
    int N, int lda, int ldb, int ldc, int kChunk) {
  __shared__ __align__(16) u16 As[64 * 40];
  __shared__ __align__(16) u16 Bs[64 * 40];
  const int n0 = blockIdx.x * 64;
  const int m0 = blockIdx.y * 64;
  const int k0 = blockIdx.z * kChunk;
  const int tid  = threadIdx.x;
  const int wave = tid >> 6, lane = tid & 63;
  const int quad = lane >> 4, lq = lane & 15;
  const int srow = tid >> 2, sgrp = tid & 3;

  f32x4 acc[4] = {{0,0,0,0},{0,0,0,0},{0,0,0,0},{0,0,0,0}};
  const u16* aptr = Ag + (size_t)(m0 + srow) * lda + k0 + sgrp * 8;
  const u16* bptr = Bg + (size_t)(n0 + srow) * ldb + k0 + sgrp * 8;
  const bool bvalid = !NGUARD || (n0 + srow) < N;

  for (int kk = 0; kk < kChunk; kk += 32) {
    uint4 av = *(const uint4*)(aptr + kk);
    uint4 bv = make_uint4(0u, 0u, 0u, 0u);
    if (bvalid) bv = *(const uint4*)(bptr + kk);
    __syncthreads();
    *(uint4*)&As[srow * 40 + sgrp * 8] = av;
    *(uint4*)&Bs[srow * 40 + sgrp * 8] = bv;
    __syncthreads();
    bf16x8 af = *(const bf16x8*)&As[(wave * 16 + lq) * 40 + quad * 8];
#pragma unroll
    for (int j = 0; j < 4; ++j) {
      bf16x8 bfr = *(const bf16x8*)&Bs[(j * 16 + lq) * 40 + quad * 8];
      acc[j] = __builtin_amdgcn_mfma_f32_16x16x32_bf16(af, bfr, acc[j], 0, 0, 0);
    }
  }
  // C/D layout: col = lane&15, row = quad*4 + reg
  const int row = m0 + wave * 16 + quad * 4;
#pragma unroll
  for (int j = 0; j < 4; ++j) {
    int col = n0 + j * 16 + lq;
    if (NGUARD && col >= N) continue;
    float bval = bias ? bias[col] : 0.f;
#pragma unroll
    for (int r = 0; r < 4; ++r) {
      float v = acc[j][r] + bval;
      size_t ci = (size_t)(row + r) * ldc + col;
      if (OUT_BF16)      ((u16*)Cout)[ci] = f2b(v);
      else if (ATOMIC)   atomicAdd((float*)Cout + ci, v);
      else               ((float*)Cout)[ci] = v;
    }
  }
}

// ---------------- per-step pointwise kernels ----------------

// softmax over 2048 cols (no max-subtraction: scores are O(1), exp is fp32-safe),
// attended = cnn * aw  -> bf16 ; also zeroes g2 for the split-K atomic GEMM.
__global__ __launch_bounds__(256) void attn_softmax(
    const float* __restrict__ preA_t, const float* __restrict__ hW,
    const float* __restrict__ cnn, u16* __restrict__ att, float* __restrict__ g2) {
  int b = blockIdx.x, tid = threadIdx.x;
  float e[8]; float sum = 0.f;
#pragma unroll
  for (int i = 0; i < 8; ++i) {
    int n = tid + i * 256;
    float s = preA_t[b * 2048 + n] + hW[b * 4096 + n];
    e[i] = __expf(s);
    sum += e[i];
  }
#pragma unroll
  for (int o = 32; o > 0; o >>= 1) sum += __shfl_down(sum, o);
  __shared__ float wsum[4];
  if ((tid & 63) == 0) wsum[tid >> 6] = sum;
  __syncthreads();
  float inv = 1.f / (wsum[0] + wsum[1] + wsum[2] + wsum[3]);
#pragma unroll
  for (int i = 0; i < 8; ++i) {
    int n = tid + i * 256;
    att[b * 2048 + n] = f2b(cnn[b * 2048 + n] * e[i] * inv);
    g2[b * 2048 + n] = 0.f;
  }
}

// gates = gA + (gB ? hW[:,2048:]) + (gC ? g2) ; LSTM pointwise (i,f,g,o order)
__global__ __launch_bounds__(256) void lstm_pw(
    const float* __restrict__ gA, int ldA,
    const float* __restrict__ gB, const float* __restrict__ gC,
    float* __restrict__ c_st, u16* __restrict__ h_out, int first) {
  int idx = blockIdx.x * 256 + threadIdx.x;   // < 128*512
  int b = idx >> 9, j = idx & 511;
  size_t ra = (size_t)b * ldA;
  float gi = gA[ra + j], gf = gA[ra + 512 + j], gg = gA[ra + 1024 + j], go = gA[ra + 1536 + j];
  if (gB) {
    size_t rb = (size_t)b * 4096 + 2048;
    gi += gB[rb + j]; gf += gB[rb + 512 + j]; gg += gB[rb + 1024 + j]; go += gB[rb + 1536 + j];
  }
  if (gC) {
    size_t rc = (size_t)b * 2048;
    gi += gC[rc + j]; gf += gC[rc + 512 + j]; gg += gC[rc + 1024 + j]; go += gC[rc + 1536 + j];
  }
  float iv = sigmoidf_(gi), fv = sigmoidf_(gf), gv = tanhf(gg), ov = sigmoidf_(go);
  float cp = first ? 0.f : c_st[idx];
  float cn = fv * cp + iv * gv;
  c_st[idx] = cn;
  h_out[idx] = f2b(ov * tanhf(cn));
}

// ---------------- host ----------------

extern "C" void kernel_launch(void* const* d_in, const int* in_sizes, int n_in,
                              void* d_out, int out_size, void* d_ws, size_t ws_size,
                              hipStream_t stream) {
  (void)in_sizes; (void)n_in; (void)out_size; (void)ws_size;
  const float* features = (const float*)d_in[0];
  const float* cnn      = (const float*)d_in[1];
  const int*   captions = (const int*)d_in[2];
  // d_in[3] lengths: unused by the reference
  const float* embed    = (const float*)d_in[4];
  const float* W_ih     = (const float*)d_in[5];
  const float* W_hh     = (const float*)d_in[6];
  const float* b_ih     = (const float*)d_in[7];
  const float* b_hh     = (const float*)d_in[8];
  const float* W_attn   = (const float*)d_in[9];
  const float* b_attn   = (const float*)d_in[10];
  const float* W_attd   = (const float*)d_in[11];
  const float* b_attd   = (const float*)d_in[12];
  const float* W_out    = (const float*)d_in[13];
  const float* b_out    = (const float*)d_in[14];

  char* ws = (char*)d_ws;
  size_t off = 0;
  auto alloc = [&](size_t bytes) { void* p = ws + off; off += (bytes + 255) & ~255UL; return p; };
  u16*   xs_tb   = (u16*)  alloc((size_t)TP1 * B_ * E_ * 2);   // [32,128,512]
  u16*   h_all   = (u16*)  alloc((size_t)TP1 * B_ * H_ * 2);   // [32,128,512] bf16 hidden
  u16*   Wh_comb = (u16*)  alloc((size_t)NHC * H_ * 2);        // [4096,512]
  u16*   W_ih_b  = (u16*)  alloc((size_t)G4 * E_ * 2);
  u16*   W_attnE = (u16*)  alloc((size_t)A_ * E_ * 2);
  u16*   W_attdE = (u16*)  alloc((size_t)E_ * E_ * 2);
  u16*   W_attdAT= (u16*)  alloc((size_t)A_ * E_ * 2);
  u16*   W_out_b = (u16*)  alloc((size_t)V_ * H_ * 2);
  u16*   Wc      = (u16*)  alloc((size_t)G4 * A_ * 2);         // [2048(g),2048(a)]
  u16*   pre_x2  = (u16*)  alloc((size_t)MPRE * E_ * 2);
  float* c_st    = (float*)alloc((size_t)B_ * H_ * 4);
  float* hW      = (float*)alloc((size_t)B_ * NHC * 4);        // [128,4096]
  float* g2      = (float*)alloc((size_t)B_ * G4 * 4);         // [128,2048]
  u16*   att     = (u16*)  alloc((size_t)B_ * A_ * 2);
  float* bias_c  = (float*)alloc((size_t)G4 * 4);

  // big precompute arrays live in d_out (dead before final GEMM overwrites it)
  float* preA = (float*)d_out;                 // [T,128,2048] fp32
  float* preG = preA + (size_t)MPRE * A_;      // [T,128,2048] fp32
  float* logits = (float*)d_out;

  // --- prep ---
  prep_xs<<<(TP1 * B_ * E_) / 256, 256, 0, stream>>>(xs_tb, features, captions, embed);
  cast_k<<<(G4 * E_) / 256, 256, 0, stream>>>(W_ih_b, W_ih, G4 * E_);
  cast_k<<<(V_ * H_) / 256, 256, 0, stream>>>(W_out_b, W_out, V_ * H_);
  cast_k<<<(G4 * H_) / 256, 256, 0, stream>>>(Wh_comb + (size_t)A_ * H_, W_hh, G4 * H_);
  prep_attn_w<<<(A_ * E_) / 256, 256, 0, stream>>>(W_attnE, Wh_comb, W_attn);
  prep_attdE<<<(E_ * E_) / 256, 256, 0, stream>>>(W_attdE, W_attd);
  prep_attdAT<<<(A_ * E_) / 256, 256, 0, stream>>>(W_attdAT, W_attd);
  add_bias2<<<G4 / 256, 256, 0, stream>>>(bias_c, b_ih, b_hh);

  // --- precompute GEMMs ---
  // Wc[g][a] = sum_e W_ih[g][e] * W_attdAT[a][e]
  gemm_nt<true, false, false><<<dim3(A_ / 64, G4 / 64, 1), 256, 0, stream>>>(
      W_ih_b, W_attdAT, Wc, nullptr, A_, 512, 512, A_, 512);
  // pre_attn = xs[1:] @ W_attnE^T + b_attn
  gemm_nt<false, false, false><<<dim3(A_ / 64, MPRE / 64, 1), 256, 0, stream>>>(
      xs_tb + (size_t)B_ * E_, W_attnE, preA, b_attn, A_, 512, 512, A_, 512);
  // pre_x2 = xs[1:] @ W_attdE^T + b_attd  (bf16)
  gemm_nt<true, false, false><<<dim3(E_ / 64, MPRE / 64, 1), 256, 0, stream>>>(
      xs_tb + (size_t)B_ * E_, W_attdE, pre_x2, b_attd, E_, 512, 512, E_, 512);
  // pre_gates = pre_x2 @ W_ih^T + (b_ih + b_hh)
  gemm_nt<false, false, false><<<dim3(G4 / 64, MPRE / 64, 1), 256, 0, stream>>>(
      pre_x2, W_ih_b, preG, bias_c, G4, 512, 512, G4, 512);
  // gates0 = features @ W_ih^T + bias  (xs_tb t=0 row block)
  gemm_nt<false, false, false><<<dim3(G4 / 64, B_ / 64, 1), 256, 0, stream>>>(
      xs_tb, W_ih_b, g2, bias_c, G4, 512, 512, G4, 512);
  // h1, c1
  lstm_pw<<<(B_ * H_) / 256, 256, 0, stream>>>(g2, G4, nullptr, nullptr, c_st, h_all, 1);

  // --- recurrence ---
  for (int t = 1; t <= T_; ++t) {
    // hW = h_{t-1} @ [W_attn_H ; W_hh]^T   [128,4096]
    gemm_nt<false, false, false><<<dim3(NHC / 64, B_ / 64, 1), 256, 0, stream>>>(
        h_all + (size_t)(t - 1) * B_ * H_, Wh_comb, hW, nullptr, NHC, 512, 512, NHC, 512);
    // softmax + attended (also zeroes g2)
    attn_softmax<<<B_, 256, 0, stream>>>(
        preA + (size_t)(t - 1) * B_ * A_, hW, cnn, att, g2);
    // g2 += attended @ Wc^T   (split-K x4, atomic)
    gemm_nt<false, true, false><<<dim3(G4 / 64, B_ / 64, 4), 256, 0, stream>>>(
        att, Wc, g2, nullptr, G4, A_, A_, G4, 512);
    // gates = preG[t-1] + hW[:,2048:] + g2 ; LSTM pointwise
    lstm_pw<<<(B_ * H_) / 256, 256, 0, stream>>>(
        preG + (size_t)(t - 1) * B_ * G4, G4, hW, g2, c_st,
        h_all + (size_t)t * B_ * H_, 0);
  }

  // --- final projection: logits = hidden @ W_out^T + b_out  [4096, 10000] ---
  gemm_nt<false, false, true><<<dim3((V_ + 63) / 64, (TP1 * B_) / 64, 1), 256, 0, stream>>>(
      h_all, W_out_b, logits, b_out, V_, 512, 512, V_, 512);
}